// Round 11
// baseline (138.988 us; speedup 1.0000x reference)
//
#include <hip/hip_runtime.h>
#include <math.h>

// ---------------------------------------------------------------------------
// CausalKernel.
//   mask_kernel: light-cone mask + Green term for all N points; wave-aggregated
//     compaction of ~9% active points with f = temporal*env/(r+1e-6); also
//     builds a zero-padded copy of the spatial kernel table in ws.
//   mode_kernel: BLOCK-OWNS-CHUNK. Each 256-thread block owns one 576-mode
//     chunk, loads it into LDS in ONE cooperative burst (kills the 36-deep
//     serial k-load latency chain that pinned rounds 2/5/8 at ~39-45us under
//     8192-way burst contention), then each wave iterates group-pairs reading
//     k via uniform-address ds_read_b128 broadcasts with register
//     double-buffering. #pragma unroll 1 keeps the loop rolled (round 7:
//     full unroll hoisted 144 ds_reads -> 256 VGPR + scratch spill disaster).
//   NOTE: dur_us carries a ~84us floor from the harness's 2x256MiB d_ws
//   poison fills inside the timed loop (measured: 2x41.5us fillBufferAligned
//   at ~81% HBM peak). Controllable part: mask (~2.5us) + mode.
// ---------------------------------------------------------------------------

constexpr int NCHUNK = 64;               // mode chunks (2^6)
constexpr int CH     = 576;              // modes per chunk = 36*16
constexpr int MPAD   = NCHUNK * CH + 64; // zero-padded k table + overrun pad
constexpr int BPC    = 16;               // blocks per chunk; grid = 64*16=1024
constexpr int DSTEPS = CH / 16;          // 36 double-steps per chunk

__global__ __launch_bounds__(256)
void mask_kernel(const float4* __restrict__ coords,
                 const float* __restrict__ massp,
                 const float* __restrict__ coupp,
                 const float* __restrict__ tk,
                 const float* __restrict__ ksp,
                 float* __restrict__ out,
                 int* __restrict__ counter,
                 int* __restrict__ list,
                 float* __restrict__ fw,
                 float* __restrict__ rw,
                 float* __restrict__ kpad,
                 int N, int M, int MT)
{
    int i = blockIdx.x * blockDim.x + threadIdx.x;

    if (i < MPAD) kpad[i] = (i < M) ? ksp[i] : 0.0f;   // padded k table
    if (i >= N) return;

    float4 c = coords[i];
    float t = c.x;
    float rsq = c.y * c.y + c.z * c.z + c.w * c.w;
    float t2  = t * t;
    bool  fl  = (t2 >= rsq) && (t >= 0.0f);            // future light cone
    float r   = sqrtf(rsq + 1e-12f);
    float g   = 0.0f;
    if (fl && (t2 > rsq) && (t > 0.0f))                // retarded Green fn
        g = (*coupp) * __expf(-(*massp) * r) / r;
    out[i] = fl ? g : 0.0f;

    unsigned long long bal = __ballot(fl);
    if (fl) {
        float tb = 0.1f * t;
        float T  = 0.0f;
        for (int m = 1; m <= MT; ++m)
            T = fmaf(tk[m - 1], __cosf(tb * (float)m), T);
        T *= __expf(-0.1f * fabsf(t));
        float f = T / (r + 1e-6f);

        int lane   = threadIdx.x & 63;
        int prefix = __popcll(bal & ((1ull << lane) - 1ull));
        int base   = 0;
        if (prefix == 0)
            base = atomicAdd(counter, __popcll(bal));   // one atomic per wave
        int first = __ffsll(bal) - 1;
        base = __shfl(base, first);
        int pos = base + prefix;
        list[pos] = i;
        fw[pos]   = f;
        rw[pos]   = r;
    }
}

__global__ __launch_bounds__(256)
void mode_kernel(const float* __restrict__ kpad,
                 float* __restrict__ out,
                 const int* __restrict__ counter,
                 const int* __restrict__ list,
                 const float* __restrict__ fw,
                 const float* __restrict__ rw)
{
    __shared__ float kch[CH + 16];        // block's chunk + prefetch pad

    int tid   = threadIdx.x;
    int lane  = tid & 63;
    int w     = tid >> 6;                               // wave in block, 0..3
    int chunk = __builtin_amdgcn_readfirstlane(blockIdx.x / BPC);
    int lb    = blockIdx.x - chunk * BPC;               // 0..BPC-1

    // one cooperative burst: 148 float4 = 2368 B (pad region of kpad is zeros)
    if (tid < (CH + 16) / 4)
        ((float4*)kch)[tid] = ((const float4*)(kpad + chunk * CH))[tid];
    __syncthreads();

    int count   = __builtin_amdgcn_readfirstlane(*counter);
    int ngroups = (count + 63) >> 6;
    int ngpairs = (ngroups + 1) >> 1;                   // 2 groups per pair
    int n0      = chunk * CH;

    for (int p = lb * 4 + w; p < ngpairs; p += BPC * 4) {
        int li0 = (p * 2) * 64 + lane;
        int li1 = li0 + 64;

        bool a0 = (li0 < count), a1 = (li1 < count);
        int   idx0 = 0, idx1 = 0;
        float r0 = 0.0f, f0 = 0.0f, r1 = 0.0f, f1 = 0.0f;
        if (a0) { idx0 = list[li0]; r0 = rw[li0]; f0 = fw[li0]; }
        if (a1) { idx1 = list[li1]; r1 = rw[li1]; f1 = fw[li1]; }

        // dp phase anchors: base = n0*r mod 2pi
        double y0 = (double)n0 * (double)r0;
        float  b0 = (float)(y0 - rint(y0 * 0.15915494309189535) * 6.283185307179586);
        double y1 = (double)n0 * (double)r1;
        float  b1 = (float)(y1 - rint(y1 * 0.15915494309189535) * 6.283185307179586);

        float t2c0 = 2.0f * __cosf(8.0f * r0);          // stride-8 Chebyshev
        float t2c1 = 2.0f * __cosf(8.0f * r1);

        float sc0[8], sp0[8], acc0[8], sc1[8], sp1[8], acc1[8];
#pragma unroll
        for (int j = 0; j < 8; ++j) {
            sc0[j] = __sinf(fmaf((float)j,       r0, b0));
            sp0[j] = __sinf(fmaf((float)(j - 8), r0, b0));
            sc1[j] = __sinf(fmaf((float)j,       r1, b1));
            sp1[j] = __sinf(fmaf((float)(j - 8), r1, b1));
            acc0[j] = 0.0f;
            acc1[j] = 0.0f;
        }

        const float4* lk = (const float4*)kch;
        float4 cA = lk[0], cB = lk[1], cC = lk[2], cD = lk[3];

#pragma unroll 1
        for (int s = 0; s < DSTEPS; ++s) {
            // issue next double-step's LDS reads; latency hides under FMAs
            float4 nA = lk[4 * s + 4], nB = lk[4 * s + 5];
            float4 nC = lk[4 * s + 6], nD = lk[4 * s + 7];

            float kv0[8] = {cA.x, cA.y, cA.z, cA.w, cB.x, cB.y, cB.z, cB.w};
            float kv1[8] = {cC.x, cC.y, cC.z, cC.w, cD.x, cD.y, cD.z, cD.w};
#pragma unroll
            for (int j = 0; j < 8; ++j) {
                acc0[j] = fmaf(kv0[j], sc0[j], acc0[j]);
                sp0[j]  = fmaf(t2c0, sc0[j], -sp0[j]);   // sin((n+8) r0)
                acc1[j] = fmaf(kv0[j], sc1[j], acc1[j]);
                sp1[j]  = fmaf(t2c1, sc1[j], -sp1[j]);   // sin((n+8) r1)
            }
#pragma unroll
            for (int j = 0; j < 8; ++j) {
                acc0[j] = fmaf(kv1[j], sp0[j], acc0[j]);
                sc0[j]  = fmaf(t2c0, sp0[j], -sc0[j]);   // sin((n+16) r0)
                acc1[j] = fmaf(kv1[j], sp1[j], acc1[j]);
                sc1[j]  = fmaf(t2c1, sp1[j], -sc1[j]);   // sin((n+16) r1)
            }
            cA = nA; cB = nB; cC = nC; cD = nD;
        }

        float S0 = ((acc0[0] + acc0[1]) + (acc0[2] + acc0[3])) +
                   ((acc0[4] + acc0[5]) + (acc0[6] + acc0[7]));
        float S1 = ((acc1[0] + acc1[1]) + (acc1[2] + acc1[3])) +
                   ((acc1[4] + acc1[5]) + (acc1[6] + acc1[7]));
        if (a0) atomicAdd(&out[idx0], S0 * f0);
        if (a1) atomicAdd(&out[idx1], S1 * f1);
    }
}

// Emergency fallback (ws too small / unexpected M): correct but slow.
__global__ __launch_bounds__(256)
void fallback_kernel(const float4* __restrict__ coords,
                     const float* __restrict__ ksp,
                     const float* __restrict__ tk,
                     const float* __restrict__ massp,
                     const float* __restrict__ coupp,
                     float* __restrict__ out, int N, int M, int MT)
{
    int i = blockIdx.x * blockDim.x + threadIdx.x;
    if (i >= N) return;
    float4 c = coords[i];
    float t = c.x;
    float rsq = c.y * c.y + c.z * c.z + c.w * c.w;
    float t2 = t * t;
    bool fl = (t2 >= rsq) && (t >= 0.0f);
    if (!fl) { out[i] = 0.0f; return; }
    float r = sqrtf(rsq + 1e-12f);
    float g = 0.0f;
    if ((t2 > rsq) && (t > 0.0f)) g = (*coupp) * __expf(-(*massp) * r) / r;
    float T = 0.0f, tb = 0.1f * t;
    for (int m = 1; m <= MT; ++m) T = fmaf(tk[m - 1], __cosf(tb * (float)m), T);
    T *= __expf(-0.1f * fabsf(t));
    float f = T / (r + 1e-6f);
    float S = 0.0f;
    for (int n0 = 0; n0 < M; n0 += 1024) {
        int nh = min(n0 + 1024, M);
        double y = (double)n0 * (double)r;
        double q = rint(y * 0.15915494309189535);
        float base = (float)(y - q * 6.283185307179586);
        float s0 = __sinf(base - r), s1 = __sinf(base);
        float tc = 2.0f * __cosf(r);
        for (int n = n0; n < nh; ++n) {
            S = fmaf(ksp[n], s1, S);
            float nx = fmaf(tc, s1, -s0);
            s0 = s1; s1 = nx;
        }
    }
    out[i] = g + S * f;
}

extern "C" void kernel_launch(void* const* d_in, const int* in_sizes, int n_in,
                              void* d_out, int out_size, void* d_ws, size_t ws_size,
                              hipStream_t stream)
{
    const float4* coords = (const float4*)d_in[0];
    const float*  ksp    = (const float*)d_in[1];
    const float*  tk     = (const float*)d_in[2];
    const float*  massp  = (const float*)d_in[3];
    const float*  coupp  = (const float*)d_in[4];
    float*        out    = (float*)d_out;

    int N  = in_sizes[0] / 4;
    int M  = in_sizes[1];
    int MT = in_sizes[2];

    size_t off_list = 16;
    size_t off_fw   = off_list + (size_t)N * 4;
    size_t off_rw   = off_fw   + (size_t)N * 4;
    size_t off_k    = off_rw   + (size_t)N * 4;
    size_t needed   = off_k    + (size_t)MPAD * 4;

    if (ws_size < needed || M > NCHUNK * CH) {
        fallback_kernel<<<(N + 255) / 256, 256, 0, stream>>>(
            coords, ksp, tk, massp, coupp, out, N, M, MT);
        return;
    }

    int*   counter = (int*)d_ws;
    int*   list    = (int*)((char*)d_ws + off_list);
    float* fw      = (float*)((char*)d_ws + off_fw);
    float* rw      = (float*)((char*)d_ws + off_rw);
    float* kpad    = (float*)((char*)d_ws + off_k);

    hipMemsetAsync(d_ws, 0, 16, stream);

    int nthreads = (N > MPAD) ? N : MPAD;
    mask_kernel<<<(nthreads + 255) / 256, 256, 0, stream>>>(
        coords, massp, coupp, tk, ksp, out, counter, list, fw, rw, kpad, N, M, MT);

    mode_kernel<<<NCHUNK * BPC, 256, 0, stream>>>(kpad, out, counter, list, fw, rw);
}

// Round 14
// 118.496 us; speedup vs baseline: 1.1729x; 1.1729x over previous
//
#include <hip/hip_runtime.h>
#include <math.h>

// ---------------------------------------------------------------------------
// CausalKernel.
//   mask_kernel: light-cone mask + Green term for all N points; wave-aggregated
//     compaction of ~9% active points with f = temporal*env/(r+1e-6); builds a
//     zero-padded spatial-kernel table in ws.
//   mode_kernel: item = (chunk, group). 64 chunks x 576 modes; grid = 3008
//     blocks (12032 waves ~= 1 item/wave). Each block stages its chunk into
//     LDS in one cooperative burst; each wave computes one 64-point group via
//     stride-8 Chebyshev sin recurrence (2 FMA/mode), reading k through
//     uniform-address ds_read_b128 broadcasts. Inner loop is a mov-free
//     ping-pong: ds_reads write DIRECTLY into the registers consumed in the
//     previous half-step (no cA=nA rotation -> no v_movs; round 11 lost 2x
//     VALU to that), #pragma unroll 1 prevents round-7's hoist/spill.
//   Failure modes mapped: r2/5/8 ~39us = serial scalar k-chain under 8192-way
//   burst; r7 125us = full-unroll hoist spill; r11 56us = rotation movs +
//   4096-wave occupancy collapse.
//   NOTE: dur_us carries a ~84us floor from the harness's 2x256MiB d_ws
//   poison fills inside the timed loop (measured r5/r8: 2x41.5us
//   fillBufferAligned at ~81% HBM peak). Controllable: mask (~2.5us) + mode.
// ---------------------------------------------------------------------------

constexpr int NCHUNK = 64;               // mode chunks (2^6)
constexpr int CH     = 576;              // modes per chunk = 36*16
constexpr int MPAD   = NCHUNK * CH + 64; // zero-padded k table + overrun pad
constexpr int BPC    = 47;               // blocks per chunk: 47*4 waves = 188 groups
constexpr int ITERS  = 18;               // 18 x 32 modes = 576

__global__ __launch_bounds__(256)
void mask_kernel(const float4* __restrict__ coords,
                 const float* __restrict__ massp,
                 const float* __restrict__ coupp,
                 const float* __restrict__ tk,
                 const float* __restrict__ ksp,
                 float* __restrict__ out,
                 int* __restrict__ counter,
                 int* __restrict__ list,
                 float* __restrict__ fw,
                 float* __restrict__ rw,
                 float* __restrict__ kpad,
                 int N, int M, int MT)
{
    int i = blockIdx.x * blockDim.x + threadIdx.x;

    if (i < MPAD) kpad[i] = (i < M) ? ksp[i] : 0.0f;   // padded k table
    if (i >= N) return;

    float4 c = coords[i];
    float t = c.x;
    float rsq = c.y * c.y + c.z * c.z + c.w * c.w;
    float t2  = t * t;
    bool  fl  = (t2 >= rsq) && (t >= 0.0f);            // future light cone
    float r   = sqrtf(rsq + 1e-12f);
    float g   = 0.0f;
    if (fl && (t2 > rsq) && (t > 0.0f))                // retarded Green fn
        g = (*coupp) * __expf(-(*massp) * r) / r;
    out[i] = fl ? g : 0.0f;

    unsigned long long bal = __ballot(fl);
    if (fl) {
        float tb = 0.1f * t;
        float T  = 0.0f;
        for (int m = 1; m <= MT; ++m)
            T = fmaf(tk[m - 1], __cosf(tb * (float)m), T);
        T *= __expf(-0.1f * fabsf(t));
        float f = T / (r + 1e-6f);

        int lane   = threadIdx.x & 63;
        int prefix = __popcll(bal & ((1ull << lane) - 1ull));
        int base   = 0;
        if (prefix == 0)
            base = atomicAdd(counter, __popcll(bal));   // one atomic per wave
        int first = __ffsll(bal) - 1;
        base = __shfl(base, first);
        int pos = base + prefix;
        list[pos] = i;
        fw[pos]   = f;
        rw[pos]   = r;
    }
}

__global__ __launch_bounds__(256)
void mode_kernel(const float* __restrict__ kpad,
                 float* __restrict__ out,
                 const int* __restrict__ counter,
                 const int* __restrict__ list,
                 const float* __restrict__ fw,
                 const float* __restrict__ rw)
{
    __shared__ float kch[CH + 32];        // chunk + prefetch-overrun pad

    int tid   = threadIdx.x;
    int lane  = tid & 63;
    int w     = tid >> 6;                               // wave in block 0..3
    int chunk = __builtin_amdgcn_readfirstlane(blockIdx.x / BPC);
    int lb    = blockIdx.x - chunk * BPC;               // 0..BPC-1
    int g0    = lb * 4 + w;                             // this wave's group

    // issue per-wave meta loads NOW (unguarded but safe: li << N); their
    // ~500cy latency hides under the LDS stage + barrier below.
    int   li  = g0 * 64 + lane;
    int   idx = list[li];
    float r   = rw[li];
    float f   = fw[li];
    int   cnt = *counter;

    // one cooperative burst: 152 float4 = 2432 B (pad region of kpad is 0)
    if (tid < (CH + 32) / 4)
        ((float4*)kch)[tid] = ((const float4*)(kpad + chunk * CH))[tid];
    __syncthreads();

    int count   = __builtin_amdgcn_readfirstlane(cnt);
    int ngroups = (count + 63) >> 6;
    int n0      = chunk * CH;

    for (int g = g0; g < ngroups; g += BPC * 4) {
        if (g != g0) {                                  // rare 2nd pass
            li = g * 64 + lane;
            idx = list[li]; r = rw[li]; f = fw[li];
        }
        bool act = (li < count);

        // dp phase anchor: b = n0*r mod 2pi
        double y = (double)n0 * (double)r;
        float  b = (float)(y - rint(y * 0.15915494309189535) * 6.283185307179586);
        float  t2c = 2.0f * __cosf(8.0f * r);           // stride-8 Chebyshev

        float sc[8], sp[8], acc[8];
#pragma unroll
        for (int j = 0; j < 8; ++j) {
            sc[j]  = __sinf(fmaf((float)j,       r, b));   // sin((n0+j) r)
            sp[j]  = __sinf(fmaf((float)(j - 8), r, b));   // sin((n0+j-8) r)
            acc[j] = 0.0f;
        }

        const float4* lk = (const float4*)kch;
        float4 kA = lk[0], kB = lk[1], kC = lk[2], kD = lk[3];

#pragma unroll 1
        for (int s = 0; s < ITERS; ++s) {
            // second half of this iteration's 32 modes
            float4 mA = lk[8 * s + 4], mB = lk[8 * s + 5];
            float4 mC = lk[8 * s + 6], mD = lk[8 * s + 7];
            {
                float kv0[8] = {kA.x, kA.y, kA.z, kA.w, kB.x, kB.y, kB.z, kB.w};
                float kv1[8] = {kC.x, kC.y, kC.z, kC.w, kD.x, kD.y, kD.z, kD.w};
#pragma unroll
                for (int j = 0; j < 8; ++j) {
                    acc[j] = fmaf(kv0[j], sc[j], acc[j]);
                    sp[j]  = fmaf(t2c, sc[j], -sp[j]);     // sin((n+8) r)
                }
#pragma unroll
                for (int j = 0; j < 8; ++j) {
                    acc[j] = fmaf(kv1[j], sp[j], acc[j]);
                    sc[j]  = fmaf(t2c, sp[j], -sc[j]);     // sin((n+16) r)
                }
            }
            // refill kA..kD for the NEXT iteration (their last use was above;
            // ds_read dest = same registers -> zero mov rotation)
            kA = lk[8 * s + 8];  kB = lk[8 * s + 9];
            kC = lk[8 * s + 10]; kD = lk[8 * s + 11];
            {
                float kv0[8] = {mA.x, mA.y, mA.z, mA.w, mB.x, mB.y, mB.z, mB.w};
                float kv1[8] = {mC.x, mC.y, mC.z, mC.w, mD.x, mD.y, mD.z, mD.w};
#pragma unroll
                for (int j = 0; j < 8; ++j) {
                    acc[j] = fmaf(kv0[j], sc[j], acc[j]);
                    sp[j]  = fmaf(t2c, sc[j], -sp[j]);     // sin((n+24) r)
                }
#pragma unroll
                for (int j = 0; j < 8; ++j) {
                    acc[j] = fmaf(kv1[j], sp[j], acc[j]);
                    sc[j]  = fmaf(t2c, sp[j], -sc[j]);     // sin((n+32) r)
                }
            }
        }

        float S = ((acc[0] + acc[1]) + (acc[2] + acc[3])) +
                  ((acc[4] + acc[5]) + (acc[6] + acc[7]));
        if (act)
            atomicAdd(&out[idx], S * f);
    }
}

// Emergency fallback (ws too small / unexpected M): correct but slow.
__global__ __launch_bounds__(256)
void fallback_kernel(const float4* __restrict__ coords,
                     const float* __restrict__ ksp,
                     const float* __restrict__ tk,
                     const float* __restrict__ massp,
                     const float* __restrict__ coupp,
                     float* __restrict__ out, int N, int M, int MT)
{
    int i = blockIdx.x * blockDim.x + threadIdx.x;
    if (i >= N) return;
    float4 c = coords[i];
    float t = c.x;
    float rsq = c.y * c.y + c.z * c.z + c.w * c.w;
    float t2 = t * t;
    bool fl = (t2 >= rsq) && (t >= 0.0f);
    if (!fl) { out[i] = 0.0f; return; }
    float r = sqrtf(rsq + 1e-12f);
    float g = 0.0f;
    if ((t2 > rsq) && (t > 0.0f)) g = (*coupp) * __expf(-(*massp) * r) / r;
    float T = 0.0f, tb = 0.1f * t;
    for (int m = 1; m <= MT; ++m) T = fmaf(tk[m - 1], __cosf(tb * (float)m), T);
    T *= __expf(-0.1f * fabsf(t));
    float f = T / (r + 1e-6f);
    float S = 0.0f;
    for (int n0 = 0; n0 < M; n0 += 1024) {
        int nh = min(n0 + 1024, M);
        double y = (double)n0 * (double)r;
        double q = rint(y * 0.15915494309189535);
        float base = (float)(y - q * 6.283185307179586);
        float s0 = __sinf(base - r), s1 = __sinf(base);
        float tc = 2.0f * __cosf(r);
        for (int n = n0; n < nh; ++n) {
            S = fmaf(ksp[n], s1, S);
            float nx = fmaf(tc, s1, -s0);
            s0 = s1; s1 = nx;
        }
    }
    out[i] = g + S * f;
}

extern "C" void kernel_launch(void* const* d_in, const int* in_sizes, int n_in,
                              void* d_out, int out_size, void* d_ws, size_t ws_size,
                              hipStream_t stream)
{
    const float4* coords = (const float4*)d_in[0];
    const float*  ksp    = (const float*)d_in[1];
    const float*  tk     = (const float*)d_in[2];
    const float*  massp  = (const float*)d_in[3];
    const float*  coupp  = (const float*)d_in[4];
    float*        out    = (float*)d_out;

    int N  = in_sizes[0] / 4;
    int M  = in_sizes[1];
    int MT = in_sizes[2];

    size_t off_list = 16;
    size_t off_fw   = off_list + (size_t)N * 4;
    size_t off_rw   = off_fw   + (size_t)N * 4;
    size_t off_k    = off_rw   + (size_t)N * 4;
    size_t needed   = off_k    + (size_t)MPAD * 4;

    // mode_kernel reads list/rw/fw unguarded up to ~2*BPC*4*64 entries;
    // requires N comfortably larger (true here: N=131072 >> 24k). If not,
    // fall back.
    if (ws_size < needed || M > NCHUNK * CH || N < NCHUNK * BPC * 8) {
        fallback_kernel<<<(N + 255) / 256, 256, 0, stream>>>(
            coords, ksp, tk, massp, coupp, out, N, M, MT);
        return;
    }

    int*   counter = (int*)d_ws;
    int*   list    = (int*)((char*)d_ws + off_list);
    float* fw      = (float*)((char*)d_ws + off_fw);
    float* rw      = (float*)((char*)d_ws + off_rw);
    float* kpad    = (float*)((char*)d_ws + off_k);

    hipMemsetAsync(d_ws, 0, 16, stream);

    int nthreads = (N > MPAD) ? N : MPAD;
    mask_kernel<<<(nthreads + 255) / 256, 256, 0, stream>>>(
        coords, massp, coupp, tk, ksp, out, counter, list, fw, rw, kpad, N, M, MT);

    mode_kernel<<<NCHUNK * BPC, 256, 0, stream>>>(kpad, out, counter, list, fw, rw);
}